// Round 1
// baseline (454.753 us; speedup 1.0000x reference)
//
#include <hip/hip_runtime.h>

typedef __bf16 bf16;
typedef __bf16 bf16x8 __attribute__((ext_vector_type(8)));
typedef float f32x4 __attribute__((ext_vector_type(4)));

#define MFMA16(a, b, c) __builtin_amdgcn_mfma_f32_16x16x32_bf16((a), (b), (c), 0, 0, 0)

constexpr int Bs = 2, Ls = 2048, DIM = 1024, NH = 16, HD = 64;
constexpr int BL = Bs * Ls;  // 4096
constexpr float EPSV = 1e-6f;
constexpr float SCALE = 0.125f;  // 1/sqrt(64)

// ---------------- fp32 -> (hi, lo) bf16 split ----------------
__global__ void split2_kernel(const float* __restrict__ src,
                              bf16* __restrict__ hi, bf16* __restrict__ lo, int n) {
  int i = blockIdx.x * blockDim.x + threadIdx.x;
  if (i < n) {
    float v = src[i];
    bf16 h = (bf16)v;
    hi[i] = h;
    lo[i] = (bf16)(v - (float)h);
  }
}

// ---------------- QKV GEMM (C = X * Wqkv^T) with fused rope/norm/blend ----------------
// 64x64 tile per block, 256 threads (4 waves), each wave owns a 16-row strip.
// Split inputs: acc += Ah*Bh + Ah*Bl + Al*Bh  (Al*Bl negligible).
__global__ __launch_bounds__(256) void qkv_gemm_kernel(
    const bf16* __restrict__ Ah, const bf16* __restrict__ Al,
    const bf16* __restrict__ Wh, const bf16* __restrict__ Wl,
    const float* __restrict__ v0,
    const float* __restrict__ rcos, const float* __restrict__ rsin,
    const float* __restrict__ lamp,
    bf16* __restrict__ qb, bf16* __restrict__ kb, bf16* __restrict__ vb,
    float* __restrict__ vout) {
  constexpr int K = DIM;  // 1024
  __shared__ alignas(16) bf16 sAh[64 * 40];  // pad to 40 elems: 80B rows, 16B-aligned
  __shared__ alignas(16) bf16 sAl[64 * 40];
  __shared__ alignas(16) bf16 sBh[64 * 40];
  __shared__ alignas(16) bf16 sBl[64 * 40];
  const int tid = threadIdx.x;
  const int w = tid >> 6;
  const int lane = tid & 63;
  const int ln = lane & 15;
  const int quad = lane >> 4;
  const int m0 = blockIdx.y * 64;  // token rows
  const int n0 = blockIdx.x * 64;  // output cols (exactly one (qkv_idx, head))
  const int r = tid >> 2;          // 0..63 staging row
  const int c8 = (tid & 3) * 8;    // staging col segment

  f32x4 acc[4] = {{0.f, 0.f, 0.f, 0.f}, {0.f, 0.f, 0.f, 0.f},
                  {0.f, 0.f, 0.f, 0.f}, {0.f, 0.f, 0.f, 0.f}};

  const bf16* pAh = Ah + (size_t)(m0 + r) * K + c8;
  const bf16* pAl = Al + (size_t)(m0 + r) * K + c8;
  const bf16* pBh = Wh + (size_t)(n0 + r) * K + c8;
  const bf16* pBl = Wl + (size_t)(n0 + r) * K + c8;

  for (int k0 = 0; k0 < K; k0 += 32) {
    *(bf16x8*)&sAh[r * 40 + c8] = *(const bf16x8*)(pAh + k0);
    *(bf16x8*)&sAl[r * 40 + c8] = *(const bf16x8*)(pAl + k0);
    *(bf16x8*)&sBh[r * 40 + c8] = *(const bf16x8*)(pBh + k0);
    *(bf16x8*)&sBl[r * 40 + c8] = *(const bf16x8*)(pBl + k0);
    __syncthreads();
    bf16x8 ah = *(const bf16x8*)&sAh[(w * 16 + ln) * 40 + quad * 8];
    bf16x8 al = *(const bf16x8*)&sAl[(w * 16 + ln) * 40 + quad * 8];
#pragma unroll
    for (int nt = 0; nt < 4; ++nt) {
      bf16x8 bh = *(const bf16x8*)&sBh[(nt * 16 + ln) * 40 + quad * 8];
      bf16x8 bl = *(const bf16x8*)&sBl[(nt * 16 + ln) * 40 + quad * 8];
      acc[nt] = MFMA16(ah, bh, acc[nt]);
      acc[nt] = MFMA16(ah, bl, acc[nt]);
      acc[nt] = MFMA16(al, bh, acc[nt]);
    }
    __syncthreads();
  }

  // Epilogue. C/D layout (16x16x32): col = lane&15 (within nt tile), row = quad*4+reg.
  const int qkvi = n0 >> 10;          // 0=q, 1=k, 2=v
  const int h = (n0 & 1023) >> 6;     // head
  const float lam = lamp[0];
  const float ratio = sqrtf(logf(2048.0f) / logf(1040.0f));

  if (qkvi == 2) {
#pragma unroll
    for (int rg = 0; rg < 4; ++rg) {
      int row = m0 + w * 16 + quad * 4 + rg;
      int b = row >> 11, l = row & 2047;
      size_t base = ((size_t)(b * NH + h) * Ls + l) * HD;
#pragma unroll
      for (int nt = 0; nt < 4; ++nt) {
        int d = nt * 16 + ln;
        float vnew = lam * acc[nt][rg] + (1.0f - lam) * v0[base + d];
        vout[base + d] = vnew;       // fp32 output #1
        vb[base + d] = (bf16)vnew;   // bf16 copy for attention
      }
    }
  } else {
    bf16* dst = (qkvi == 0) ? qb : kb;
#pragma unroll
    for (int rg = 0; rg < 4; ++rg) {
      int row = m0 + w * 16 + quad * 4 + rg;
      int b = row >> 11, l = row & 2047;
      float vals[4];
#pragma unroll
      for (int nt = 0; nt < 4; ++nt) vals[nt] = acc[nt][rg];
      // RoPE: pair (d, d+32) == (vals[nt], vals[nt+2]) for nt in {0,1}, j = nt*16+ln
#pragma unroll
      for (int nt = 0; nt < 2; ++nt) {
        int j = nt * 16 + ln;
        float c = rcos[l * 32 + j], s = rsin[l * 32 + j];
        float x1 = vals[nt], x2 = vals[nt + 2];
        vals[nt] = x1 * c + x2 * s;
        vals[nt + 2] = -x1 * s + x2 * c;
      }
      if (qkvi == 1) {
#pragma unroll
        for (int nt = 0; nt < 4; ++nt) vals[nt] *= ratio;
      }
      // RMS norm over the head's 64 dims: quad shuffle-reduce (16 lanes x 4 regs)
      float ms = vals[0] * vals[0] + vals[1] * vals[1] + vals[2] * vals[2] + vals[3] * vals[3];
      ms += __shfl_xor(ms, 1);
      ms += __shfl_xor(ms, 2);
      ms += __shfl_xor(ms, 4);
      ms += __shfl_xor(ms, 8);
      float rn = rsqrtf(ms * (1.0f / 64.0f) + EPSV);
      size_t base = ((size_t)(b * NH + h) * Ls + l) * HD;
#pragma unroll
      for (int nt = 0; nt < 4; ++nt) dst[base + nt * 16 + ln] = (bf16)(vals[nt] * rn);
    }
  }
}

// ---------------- Flash attention: one block per (b, h, 64-row q tile) ----------------
__global__ __launch_bounds__(256) void flash_kernel(
    const bf16* __restrict__ qg, const bf16* __restrict__ kg, const bf16* __restrict__ vg,
    bf16* __restrict__ aoh, bf16* __restrict__ aol) {
  __shared__ alignas(16) bf16 sQ[64 * 72];   // 144B rows, 16B-aligned
  __shared__ alignas(16) bf16 sK[64 * 72];
  __shared__ alignas(16) bf16 sVT[64 * 72];  // V transposed: [d][key]
  __shared__ alignas(16) bf16 sP[64 * 72];
  const int tid = threadIdx.x;
  const int w = tid >> 6, lane = tid & 63, ln = lane & 15, quad = lane >> 4;
  const int bx = blockIdx.x;
  const int qt = bx & 31, h = (bx >> 5) & 15, b = bx >> 9;
  const bf16* Qh = qg + (size_t)(b * NH + h) * Ls * HD;
  const bf16* Kh = kg + (size_t)(b * NH + h) * Ls * HD;
  const bf16* Vh = vg + (size_t)(b * NH + h) * Ls * HD;
  const int q0 = qt * 64;

  // stage Q tile (64x64 = 512 vec8 segments, 2 per thread)
#pragma unroll
  for (int s = 0; s < 2; ++s) {
    int e = tid + s * 256;
    int row = e >> 3, c8 = (e & 7) * 8;
    *(bf16x8*)&sQ[row * 72 + c8] = *(const bf16x8*)&Qh[(q0 + row) * HD + c8];
  }

  f32x4 O[4] = {{0.f, 0.f, 0.f, 0.f}, {0.f, 0.f, 0.f, 0.f},
                {0.f, 0.f, 0.f, 0.f}, {0.f, 0.f, 0.f, 0.f}};
  float m_i[4], l_i[4];
#pragma unroll
  for (int i2 = 0; i2 < 4; ++i2) { m_i[i2] = -1e30f; l_i[i2] = 0.f; }

  for (int kt = 0; kt < 32; ++kt) {
    __syncthreads();  // protect sK/sVT/sP from prior iteration's readers
    const int k0 = kt * 64;
#pragma unroll
    for (int s = 0; s < 2; ++s) {
      int e = tid + s * 256;
      int row = e >> 3, c8 = (e & 7) * 8;
      *(bf16x8*)&sK[row * 72 + c8] = *(const bf16x8*)&Kh[(k0 + row) * HD + c8];
      bf16x8 vv = *(const bf16x8*)&Vh[(k0 + row) * HD + c8];
#pragma unroll
      for (int j = 0; j < 8; ++j) sVT[(c8 + j) * 72 + row] = vv[j];
    }
    __syncthreads();

    // S = Q * K^T  (rows: q strip of this wave, cols: key in tile)
    bf16x8 aq0 = *(const bf16x8*)&sQ[(w * 16 + ln) * 72 + quad * 8];
    bf16x8 aq1 = *(const bf16x8*)&sQ[(w * 16 + ln) * 72 + 32 + quad * 8];
    f32x4 S[4];
#pragma unroll
    for (int nt = 0; nt < 4; ++nt) {
      f32x4 z = {0.f, 0.f, 0.f, 0.f};
      bf16x8 bk0 = *(const bf16x8*)&sK[(nt * 16 + ln) * 72 + quad * 8];
      bf16x8 bk1 = *(const bf16x8*)&sK[(nt * 16 + ln) * 72 + 32 + quad * 8];
      z = MFMA16(aq0, bk0, z);
      z = MFMA16(aq1, bk1, z);
      S[nt] = z;
    }

    // online softmax per row (row = quad*4+rg, same for all 16 lanes of a quad)
#pragma unroll
    for (int rg = 0; rg < 4; ++rg) {
      float x0 = S[0][rg] * SCALE, x1 = S[1][rg] * SCALE;
      float x2 = S[2][rg] * SCALE, x3 = S[3][rg] * SCALE;
      float mx = fmaxf(fmaxf(x0, x1), fmaxf(x2, x3));
      mx = fmaxf(mx, __shfl_xor(mx, 1));
      mx = fmaxf(mx, __shfl_xor(mx, 2));
      mx = fmaxf(mx, __shfl_xor(mx, 4));
      mx = fmaxf(mx, __shfl_xor(mx, 8));
      float mnew = fmaxf(m_i[rg], mx);
      float alpha = __expf(m_i[rg] - mnew);
      float p0 = __expf(x0 - mnew), p1 = __expf(x1 - mnew);
      float p2 = __expf(x2 - mnew), p3 = __expf(x3 - mnew);
      float rs = p0 + p1 + p2 + p3;
      rs += __shfl_xor(rs, 1);
      rs += __shfl_xor(rs, 2);
      rs += __shfl_xor(rs, 4);
      rs += __shfl_xor(rs, 8);
      l_i[rg] = l_i[rg] * alpha + rs;
      m_i[rg] = mnew;
      O[0][rg] *= alpha; O[1][rg] *= alpha; O[2][rg] *= alpha; O[3][rg] *= alpha;
      int prow = (w * 16 + quad * 4 + rg) * 72 + ln;
      sP[prow] = (bf16)p0;
      sP[prow + 16] = (bf16)p1;
      sP[prow + 32] = (bf16)p2;
      sP[prow + 48] = (bf16)p3;
    }
    __syncthreads();

    // O += P * V   (B operand from sVT: B[k=key][n=d] at sVT[d*72 + key])
    bf16x8 ap0 = *(const bf16x8*)&sP[(w * 16 + ln) * 72 + quad * 8];
    bf16x8 ap1 = *(const bf16x8*)&sP[(w * 16 + ln) * 72 + 32 + quad * 8];
#pragma unroll
    for (int nt = 0; nt < 4; ++nt) {
      bf16x8 bv0 = *(const bf16x8*)&sVT[(nt * 16 + ln) * 72 + quad * 8];
      bf16x8 bv1 = *(const bf16x8*)&sVT[(nt * 16 + ln) * 72 + 32 + quad * 8];
      O[nt] = MFMA16(ap0, bv0, O[nt]);
      O[nt] = MFMA16(ap1, bv1, O[nt]);
    }
  }

  // epilogue: normalize and store attn-out as hi/lo bf16 split, (b,l,dim) layout
#pragma unroll
  for (int rg = 0; rg < 4; ++rg) {
    float inv = 1.0f / l_i[rg];
    int l = q0 + w * 16 + quad * 4 + rg;
    size_t orow = ((size_t)b * Ls + l) * DIM + h * HD;
#pragma unroll
    for (int nt = 0; nt < 4; ++nt) {
      float o = O[nt][rg] * inv;
      bf16 hi = (bf16)o;
      aoh[orow + nt * 16 + ln] = hi;
      aol[orow + nt * 16 + ln] = (bf16)(o - (float)hi);
    }
  }
}

// ---------------- proj GEMM (out = AO * Wproj^T), split inputs, fp32 out ----------------
__global__ __launch_bounds__(256) void proj_gemm_kernel(
    const bf16* __restrict__ Ah, const bf16* __restrict__ Al,
    const bf16* __restrict__ Wh, const bf16* __restrict__ Wl,
    float* __restrict__ out) {
  constexpr int K = DIM;
  __shared__ alignas(16) bf16 sAh[64 * 40];
  __shared__ alignas(16) bf16 sAl[64 * 40];
  __shared__ alignas(16) bf16 sBh[64 * 40];
  __shared__ alignas(16) bf16 sBl[64 * 40];
  const int tid = threadIdx.x;
  const int w = tid >> 6;
  const int lane = tid & 63;
  const int ln = lane & 15;
  const int quad = lane >> 4;
  const int m0 = blockIdx.y * 64;
  const int n0 = blockIdx.x * 64;
  const int r = tid >> 2;
  const int c8 = (tid & 3) * 8;

  f32x4 acc[4] = {{0.f, 0.f, 0.f, 0.f}, {0.f, 0.f, 0.f, 0.f},
                  {0.f, 0.f, 0.f, 0.f}, {0.f, 0.f, 0.f, 0.f}};

  const bf16* pAh = Ah + (size_t)(m0 + r) * K + c8;
  const bf16* pAl = Al + (size_t)(m0 + r) * K + c8;
  const bf16* pBh = Wh + (size_t)(n0 + r) * K + c8;
  const bf16* pBl = Wl + (size_t)(n0 + r) * K + c8;

  for (int k0 = 0; k0 < K; k0 += 32) {
    *(bf16x8*)&sAh[r * 40 + c8] = *(const bf16x8*)(pAh + k0);
    *(bf16x8*)&sAl[r * 40 + c8] = *(const bf16x8*)(pAl + k0);
    *(bf16x8*)&sBh[r * 40 + c8] = *(const bf16x8*)(pBh + k0);
    *(bf16x8*)&sBl[r * 40 + c8] = *(const bf16x8*)(pBl + k0);
    __syncthreads();
    bf16x8 ah = *(const bf16x8*)&sAh[(w * 16 + ln) * 40 + quad * 8];
    bf16x8 al = *(const bf16x8*)&sAl[(w * 16 + ln) * 40 + quad * 8];
#pragma unroll
    for (int nt = 0; nt < 4; ++nt) {
      bf16x8 bh = *(const bf16x8*)&sBh[(nt * 16 + ln) * 40 + quad * 8];
      bf16x8 bl = *(const bf16x8*)&sBl[(nt * 16 + ln) * 40 + quad * 8];
      acc[nt] = MFMA16(ah, bh, acc[nt]);
      acc[nt] = MFMA16(ah, bl, acc[nt]);
      acc[nt] = MFMA16(al, bh, acc[nt]);
    }
    __syncthreads();
  }
#pragma unroll
  for (int rg = 0; rg < 4; ++rg) {
    int row = m0 + w * 16 + quad * 4 + rg;
    size_t o = (size_t)row * DIM + n0;
#pragma unroll
    for (int nt = 0; nt < 4; ++nt) out[o + nt * 16 + ln] = acc[nt][rg];
  }
}

extern "C" void kernel_launch(void* const* d_in, const int* in_sizes, int n_in,
                              void* d_out, int out_size, void* d_ws, size_t ws_size,
                              hipStream_t stream) {
  (void)in_sizes; (void)n_in; (void)out_size; (void)ws_size;
  const float* x = (const float*)d_in[0];
  const float* v0 = (const float*)d_in[1];
  const float* rcos = (const float*)d_in[2];
  const float* rsin = (const float*)d_in[3];
  const float* wqkv = (const float*)d_in[4];
  const float* wproj = (const float*)d_in[5];
  const float* lamp = (const float*)d_in[6];
  float* out = (float*)d_out;
  float* vout = out + (size_t)BL * DIM;  // output #1: blended v, (B,H,L,HD)

  char* p = (char*)d_ws;
  auto take = [&](size_t n) { char* q = p; p += ((n + 255) / 256) * 256; return q; };
  bf16* xh = (bf16*)take((size_t)BL * DIM * 2);
  bf16* xl = (bf16*)take((size_t)BL * DIM * 2);
  bf16* wqh = (bf16*)take((size_t)3 * DIM * DIM * 2);
  bf16* wql = (bf16*)take((size_t)3 * DIM * DIM * 2);
  bf16* wph = (bf16*)take((size_t)DIM * DIM * 2);
  bf16* wpl = (bf16*)take((size_t)DIM * DIM * 2);
  bf16* qb = (bf16*)take((size_t)BL * DIM * 2);
  bf16* kb = (bf16*)take((size_t)BL * DIM * 2);
  bf16* vb = (bf16*)take((size_t)BL * DIM * 2);
  // x is dead after qkv_gemm; overlay attn-out split on its region (stream-ordered)
  bf16* aoh = xh;
  bf16* aol = xl;

  const int nx = BL * DIM;       // 4,194,304
  const int nw = 3 * DIM * DIM;  // 3,145,728
  const int np = DIM * DIM;      // 1,048,576
  split2_kernel<<<dim3((nx + 255) / 256), dim3(256), 0, stream>>>(x, xh, xl, nx);
  split2_kernel<<<dim3((nw + 255) / 256), dim3(256), 0, stream>>>(wqkv, wqh, wql, nw);
  split2_kernel<<<dim3((np + 255) / 256), dim3(256), 0, stream>>>(wproj, wph, wpl, np);

  qkv_gemm_kernel<<<dim3(3 * DIM / 64, BL / 64), dim3(256), 0, stream>>>(
      xh, xl, wqh, wql, v0, rcos, rsin, lamp, qb, kb, vb, vout);

  flash_kernel<<<dim3(Bs * NH * (Ls / 64)), dim3(256), 0, stream>>>(qb, kb, vb, aoh, aol);

  proj_gemm_kernel<<<dim3(DIM / 64, BL / 64), dim3(256), 0, stream>>>(aoh, aol, wph, wpl, out);
}

// Round 2
// 333.683 us; speedup vs baseline: 1.3628x; 1.3628x over previous
//
#include <hip/hip_runtime.h>

typedef __bf16 bf16;
typedef __bf16 bf16x8 __attribute__((ext_vector_type(8)));
typedef float f32x4 __attribute__((ext_vector_type(4)));

#define MFMA16(a, b, c) __builtin_amdgcn_mfma_f32_16x16x32_bf16((a), (b), (c), 0, 0, 0)

constexpr int Bs = 2, Ls = 2048, DIM = 1024, NH = 16, HD = 64;
constexpr int BL = Bs * Ls;  // 4096
constexpr float EPSV = 1e-6f;
constexpr float SCALE = 0.125f;  // 1/sqrt(64)

// async global->LDS, 16B per lane. LDS dest = wave-uniform base + lane*16.
__device__ __forceinline__ void async16(void* lds, const void* g) {
  __builtin_amdgcn_global_load_lds((const __attribute__((address_space(1))) void*)g,
                                   (__attribute__((address_space(3))) void*)lds, 16, 0, 0);
}

// ---------------- fp32 -> (hi, lo) bf16 split ----------------
__global__ void split2_kernel(const float* __restrict__ src,
                              bf16* __restrict__ hi, bf16* __restrict__ lo, int n) {
  int i = blockIdx.x * blockDim.x + threadIdx.x;
  if (i < n) {
    float v = src[i];
    bf16 h = (bf16)v;
    hi[i] = h;
    lo[i] = (bf16)(v - (float)h);
  }
}

// ============ QKV GEMM: 128x128 tile, global_load_lds, fused rope/norm/blend ============
// 256 thr = 4 waves in 2x2; each wave owns a 64x64 quadrant (4x4 16x16 tiles).
// LDS [128][32] bf16 unpadded (required by global_load_lds) with XOR swizzle:
// physical 16B-chunk c of row r holds global chunk c^(r&3) -> frag reads are ~2-way (free).
__global__ __launch_bounds__(256) void qkv_gemm_kernel(
    const bf16* __restrict__ Ah, const bf16* __restrict__ Al,
    const bf16* __restrict__ Wh, const bf16* __restrict__ Wl,
    const float* __restrict__ v0,
    const float* __restrict__ rcos, const float* __restrict__ rsin,
    const float* __restrict__ lamp,
    bf16* __restrict__ qb, bf16* __restrict__ kb, bf16* __restrict__ vbT,
    float* __restrict__ vout) {
  constexpr int K = DIM;
  __shared__ alignas(16) bf16 sAh[128 * 32];
  __shared__ alignas(16) bf16 sAl[128 * 32];
  __shared__ alignas(16) bf16 sBh[128 * 32];
  __shared__ alignas(16) bf16 sBl[128 * 32];
  const int tid = threadIdx.x;
  const int w = tid >> 6, lane = tid & 63, ln = lane & 15, quad = lane >> 4;
  const int wm = w >> 1, wn = w & 1;
  const int m0 = blockIdx.y * 128, n0 = blockIdx.x * 128;

  // staging map: element-16B index e = tid (+256 for 2nd call); row=e>>2, swizzled col
  const int sr = tid >> 2;                     // 0..63 (2nd call: +64)
  const int sc = (((tid & 3) ^ (sr & 3)) * 8); // elems; same xor row-bits for both calls
  const size_t rstep = (size_t)64 * K;
  const bf16* gAh = Ah + (size_t)(m0 + sr) * K + sc;
  const bf16* gAl = Al + (size_t)(m0 + sr) * K + sc;
  const bf16* gBh = Wh + (size_t)(n0 + sr) * K + sc;
  const bf16* gBl = Wl + (size_t)(n0 + sr) * K + sc;

  f32x4 acc[4][4] = {};

  for (int k0 = 0; k0 < K; k0 += 32) {
    async16(&sAh[tid * 8], gAh + k0);
    async16(&sAh[(tid + 256) * 8], gAh + rstep + k0);
    async16(&sAl[tid * 8], gAl + k0);
    async16(&sAl[(tid + 256) * 8], gAl + rstep + k0);
    async16(&sBh[tid * 8], gBh + k0);
    async16(&sBh[(tid + 256) * 8], gBh + rstep + k0);
    async16(&sBl[tid * 8], gBl + k0);
    async16(&sBl[(tid + 256) * 8], gBl + rstep + k0);
    __syncthreads();  // compiler drains vmcnt before s_barrier

    bf16x8 ah[4], al[4];
#pragma unroll
    for (int mi = 0; mi < 4; ++mi) {
      int r = wm * 64 + mi * 16 + ln;
      int off = r * 32 + ((quad ^ (r & 3)) * 8);
      ah[mi] = *(const bf16x8*)&sAh[off];
      al[mi] = *(const bf16x8*)&sAl[off];
    }
#pragma unroll
    for (int ni = 0; ni < 4; ++ni) {
      int r = wn * 64 + ni * 16 + ln;
      int off = r * 32 + ((quad ^ (r & 3)) * 8);
      bf16x8 bh = *(const bf16x8*)&sBh[off];
      bf16x8 bl = *(const bf16x8*)&sBl[off];
#pragma unroll
      for (int mi = 0; mi < 4; ++mi) {
        acc[mi][ni] = MFMA16(ah[mi], bh, acc[mi][ni]);
        acc[mi][ni] = MFMA16(al[mi], bh, acc[mi][ni]);
        acc[mi][ni] = MFMA16(ah[mi], bl, acc[mi][ni]);
      }
    }
    __syncthreads();
  }

  // Epilogue. Wave covers one head (64 cols): nb = n0+wn*64 inside one qkv section.
  // C/D layout (16x16x32): col = ln (within ni tile), row = quad*4+rg (within mi tile).
  const int nb = n0 + wn * 64;
  const int nsec = nb >> 10;        // 0=q, 1=k, 2=v
  const int h = (nb & 1023) >> 6;   // head

  if (nsec == 2) {
    const float lam = lamp[0];
#pragma unroll
    for (int mi = 0; mi < 4; ++mi) {
#pragma unroll
      for (int rg = 0; rg < 4; ++rg) {
        int row = m0 + wm * 64 + mi * 16 + quad * 4 + rg;
        int b = row >> 11, l = row & 2047;
        size_t base = ((size_t)(b * NH + h) * Ls + l) * HD;
        size_t tb = ((size_t)(b * NH + h) * HD) * Ls + l;
#pragma unroll
        for (int ni = 0; ni < 4; ++ni) {
          int d = ni * 16 + ln;
          float vnew = lam * acc[mi][ni][rg] + (1.0f - lam) * v0[base + d];
          vout[base + d] = vnew;                 // fp32 output #1 (b,h,l,d)
          vbT[tb + (size_t)d * Ls] = (bf16)vnew; // pre-transposed (b,h,d,l) for flash PV
        }
      }
    }
  } else {
    bf16* dst = nsec ? kb : qb;
    const float ratio = sqrtf(logf(2048.0f) / logf(1040.0f));
#pragma unroll
    for (int mi = 0; mi < 4; ++mi) {
#pragma unroll
      for (int rg = 0; rg < 4; ++rg) {
        int row = m0 + wm * 64 + mi * 16 + quad * 4 + rg;
        int b = row >> 11, l = row & 2047;
        float vals[4];
#pragma unroll
        for (int ni = 0; ni < 4; ++ni) vals[ni] = acc[mi][ni][rg];
        // RoPE: pair (d, d+32) == (vals[t], vals[t+2]), j = t*16+ln
#pragma unroll
        for (int t = 0; t < 2; ++t) {
          int j = t * 16 + ln;
          float c = rcos[l * 32 + j], s = rsin[l * 32 + j];
          float x1 = vals[t], x2 = vals[t + 2];
          vals[t] = x1 * c + x2 * s;
          vals[t + 2] = -x1 * s + x2 * c;
        }
        if (nsec) {
#pragma unroll
          for (int ni = 0; ni < 4; ++ni) vals[ni] *= ratio;
        }
        float ms = vals[0] * vals[0] + vals[1] * vals[1] + vals[2] * vals[2] + vals[3] * vals[3];
        ms += __shfl_xor(ms, 1);
        ms += __shfl_xor(ms, 2);
        ms += __shfl_xor(ms, 4);
        ms += __shfl_xor(ms, 8);
        float rn = rsqrtf(ms * (1.0f / 64.0f) + EPSV);
        size_t base = ((size_t)(b * NH + h) * Ls + l) * HD;
#pragma unroll
        for (int ni = 0; ni < 4; ++ni) dst[base + ni * 16 + ln] = (bf16)(vals[ni] * rn);
      }
    }
  }
}

// ============ Flash attention, no-max softmax (scores bounded by 8.4 after RMS norm) ============
// One block per (b, h, 64-row q tile). V arrives pre-transposed (b,h,d,l): no in-loop transpose.
__global__ __launch_bounds__(256) void flash_kernel(
    const bf16* __restrict__ qg, const bf16* __restrict__ kg, const bf16* __restrict__ vtg,
    bf16* __restrict__ aoh, bf16* __restrict__ aol) {
  __shared__ alignas(16) bf16 sQ[64 * 72];   // stride 72 elems = 144B: frag b128 ~2-way (free)
  __shared__ alignas(16) bf16 sK[64 * 72];
  __shared__ alignas(16) bf16 sVT[64 * 72];  // [d][key]
  __shared__ alignas(16) bf16 sP[64 * 72];
  const int tid = threadIdx.x;
  const int w = tid >> 6, lane = tid & 63, ln = lane & 15, quad = lane >> 4;
  const int bx = blockIdx.x;
  const int qt = bx & 31, h = (bx >> 5) & 15, b = bx >> 9;
  const bf16* Qh = qg + (size_t)(b * NH + h) * Ls * HD;
  const bf16* Kh = kg + (size_t)(b * NH + h) * Ls * HD;
  const bf16* VTh = vtg + (size_t)(b * NH + h) * HD * Ls;  // [d][l]
  const int q0 = qt * 64;

  // stage Q tile once; hoist A-frags out of the k-loop
#pragma unroll
  for (int s = 0; s < 2; ++s) {
    int e = tid + s * 256;
    int row = e >> 3, c8 = (e & 7) * 8;
    *(bf16x8*)&sQ[row * 72 + c8] = *(const bf16x8*)&Qh[(q0 + row) * HD + c8];
  }
  __syncthreads();
  const bf16x8 aq0 = *(const bf16x8*)&sQ[(w * 16 + ln) * 72 + quad * 8];
  const bf16x8 aq1 = *(const bf16x8*)&sQ[(w * 16 + ln) * 72 + 32 + quad * 8];

  f32x4 O[4] = {{0.f, 0.f, 0.f, 0.f}, {0.f, 0.f, 0.f, 0.f},
                {0.f, 0.f, 0.f, 0.f}, {0.f, 0.f, 0.f, 0.f}};
  float rsum[4] = {0.f, 0.f, 0.f, 0.f};  // per-lane partial row sums; reduced once at end

  for (int kt = 0; kt < 32; ++kt) {
    __syncthreads();  // protect sK/sVT (PV of prev iter) before restaging
    const int k0 = kt * 64;
#pragma unroll
    for (int s = 0; s < 2; ++s) {
      int e = tid + s * 256;
      int row = e >> 3, c8 = (e & 7) * 8;
      *(bf16x8*)&sK[row * 72 + c8] = *(const bf16x8*)&Kh[(k0 + row) * HD + c8];
      *(bf16x8*)&sVT[row * 72 + c8] = *(const bf16x8*)&VTh[(size_t)row * Ls + k0 + c8];
    }
    __syncthreads();

    // S = Q K^T
    f32x4 S[4];
#pragma unroll
    for (int nt = 0; nt < 4; ++nt) {
      f32x4 z = {0.f, 0.f, 0.f, 0.f};
      bf16x8 bk0 = *(const bf16x8*)&sK[(nt * 16 + ln) * 72 + quad * 8];
      bf16x8 bk1 = *(const bf16x8*)&sK[(nt * 16 + ln) * 72 + 32 + quad * 8];
      z = MFMA16(aq0, bk0, z);
      z = MFMA16(aq1, bk1, z);
      S[nt] = z;
    }

    // p = exp(score): no max-shift needed (|score| <= ~8.4 -> exp <= ~4.4e3, sum <= 9e6)
#pragma unroll
    for (int rg = 0; rg < 4; ++rg) {
      int prow = (w * 16 + quad * 4 + rg) * 72 + ln;
#pragma unroll
      for (int nt = 0; nt < 4; ++nt) {
        float p = __expf(S[nt][rg] * SCALE);
        rsum[rg] += p;
        sP[prow + nt * 16] = (bf16)p;
      }
    }
    __syncthreads();

    // O += P V
    bf16x8 ap0 = *(const bf16x8*)&sP[(w * 16 + ln) * 72 + quad * 8];
    bf16x8 ap1 = *(const bf16x8*)&sP[(w * 16 + ln) * 72 + 32 + quad * 8];
#pragma unroll
    for (int nt = 0; nt < 4; ++nt) {
      bf16x8 bv0 = *(const bf16x8*)&sVT[(nt * 16 + ln) * 72 + quad * 8];
      bf16x8 bv1 = *(const bf16x8*)&sVT[(nt * 16 + ln) * 72 + 32 + quad * 8];
      O[nt] = MFMA16(ap0, bv0, O[nt]);
      O[nt] = MFMA16(ap1, bv1, O[nt]);
    }
  }

  // epilogue: row-sum reduce (once), normalize, hi/lo split store in (b,l,dim)
#pragma unroll
  for (int rg = 0; rg < 4; ++rg) {
    float rs = rsum[rg];
    rs += __shfl_xor(rs, 1);
    rs += __shfl_xor(rs, 2);
    rs += __shfl_xor(rs, 4);
    rs += __shfl_xor(rs, 8);
    float inv = 1.0f / rs;
    int l = q0 + w * 16 + quad * 4 + rg;
    size_t orow = ((size_t)b * Ls + l) * DIM + h * HD;
#pragma unroll
    for (int nt = 0; nt < 4; ++nt) {
      float o = O[nt][rg] * inv;
      bf16 hi = (bf16)o;
      aoh[orow + nt * 16 + ln] = hi;
      aol[orow + nt * 16 + ln] = (bf16)(o - (float)hi);
    }
  }
}

// ============ proj GEMM: same 128x128 m97-style core, fp32 out ============
__global__ __launch_bounds__(256) void proj_gemm_kernel(
    const bf16* __restrict__ Ah, const bf16* __restrict__ Al,
    const bf16* __restrict__ Wh, const bf16* __restrict__ Wl,
    float* __restrict__ out) {
  constexpr int K = DIM;
  __shared__ alignas(16) bf16 sAh[128 * 32];
  __shared__ alignas(16) bf16 sAl[128 * 32];
  __shared__ alignas(16) bf16 sBh[128 * 32];
  __shared__ alignas(16) bf16 sBl[128 * 32];
  const int tid = threadIdx.x;
  const int w = tid >> 6, lane = tid & 63, ln = lane & 15, quad = lane >> 4;
  const int wm = w >> 1, wn = w & 1;
  const int m0 = blockIdx.y * 128, n0 = blockIdx.x * 128;
  const int sr = tid >> 2;
  const int sc = (((tid & 3) ^ (sr & 3)) * 8);
  const size_t rstep = (size_t)64 * K;
  const bf16* gAh = Ah + (size_t)(m0 + sr) * K + sc;
  const bf16* gAl = Al + (size_t)(m0 + sr) * K + sc;
  const bf16* gBh = Wh + (size_t)(n0 + sr) * K + sc;
  const bf16* gBl = Wl + (size_t)(n0 + sr) * K + sc;

  f32x4 acc[4][4] = {};

  for (int k0 = 0; k0 < K; k0 += 32) {
    async16(&sAh[tid * 8], gAh + k0);
    async16(&sAh[(tid + 256) * 8], gAh + rstep + k0);
    async16(&sAl[tid * 8], gAl + k0);
    async16(&sAl[(tid + 256) * 8], gAl + rstep + k0);
    async16(&sBh[tid * 8], gBh + k0);
    async16(&sBh[(tid + 256) * 8], gBh + rstep + k0);
    async16(&sBl[tid * 8], gBl + k0);
    async16(&sBl[(tid + 256) * 8], gBl + rstep + k0);
    __syncthreads();

    bf16x8 ah[4], al[4];
#pragma unroll
    for (int mi = 0; mi < 4; ++mi) {
      int r = wm * 64 + mi * 16 + ln;
      int off = r * 32 + ((quad ^ (r & 3)) * 8);
      ah[mi] = *(const bf16x8*)&sAh[off];
      al[mi] = *(const bf16x8*)&sAl[off];
    }
#pragma unroll
    for (int ni = 0; ni < 4; ++ni) {
      int r = wn * 64 + ni * 16 + ln;
      int off = r * 32 + ((quad ^ (r & 3)) * 8);
      bf16x8 bh = *(const bf16x8*)&sBh[off];
      bf16x8 bl = *(const bf16x8*)&sBl[off];
#pragma unroll
      for (int mi = 0; mi < 4; ++mi) {
        acc[mi][ni] = MFMA16(ah[mi], bh, acc[mi][ni]);
        acc[mi][ni] = MFMA16(al[mi], bh, acc[mi][ni]);
        acc[mi][ni] = MFMA16(ah[mi], bl, acc[mi][ni]);
      }
    }
    __syncthreads();
  }

#pragma unroll
  for (int mi = 0; mi < 4; ++mi) {
#pragma unroll
    for (int rg = 0; rg < 4; ++rg) {
      int row = m0 + wm * 64 + mi * 16 + quad * 4 + rg;
      size_t o = (size_t)row * DIM + n0 + wn * 64;
#pragma unroll
      for (int ni = 0; ni < 4; ++ni) out[o + ni * 16 + ln] = acc[mi][ni][rg];
    }
  }
}

extern "C" void kernel_launch(void* const* d_in, const int* in_sizes, int n_in,
                              void* d_out, int out_size, void* d_ws, size_t ws_size,
                              hipStream_t stream) {
  (void)in_sizes; (void)n_in; (void)out_size; (void)ws_size;
  const float* x = (const float*)d_in[0];
  const float* v0 = (const float*)d_in[1];
  const float* rcos = (const float*)d_in[2];
  const float* rsin = (const float*)d_in[3];
  const float* wqkv = (const float*)d_in[4];
  const float* wproj = (const float*)d_in[5];
  const float* lamp = (const float*)d_in[6];
  float* out = (float*)d_out;
  float* vout = out + (size_t)BL * DIM;  // output #1: blended v, (B,H,L,HD)

  char* p = (char*)d_ws;
  auto take = [&](size_t n) { char* q = p; p += ((n + 255) / 256) * 256; return q; };
  bf16* xh = (bf16*)take((size_t)BL * DIM * 2);
  bf16* xl = (bf16*)take((size_t)BL * DIM * 2);
  bf16* wqh = (bf16*)take((size_t)3 * DIM * DIM * 2);
  bf16* wql = (bf16*)take((size_t)3 * DIM * DIM * 2);
  bf16* wph = (bf16*)take((size_t)DIM * DIM * 2);
  bf16* wpl = (bf16*)take((size_t)DIM * DIM * 2);
  bf16* qb = (bf16*)take((size_t)BL * DIM * 2);
  bf16* kb = (bf16*)take((size_t)BL * DIM * 2);
  bf16* vbT = (bf16*)take((size_t)BL * DIM * 2);  // (b,h,d,l) pre-transposed for flash
  // x is dead after qkv_gemm; overlay attn-out split on its region (stream-ordered)
  bf16* aoh = xh;
  bf16* aol = xl;

  const int nx = BL * DIM;
  const int nw = 3 * DIM * DIM;
  const int np = DIM * DIM;
  split2_kernel<<<dim3((nx + 255) / 256), dim3(256), 0, stream>>>(x, xh, xl, nx);
  split2_kernel<<<dim3((nw + 255) / 256), dim3(256), 0, stream>>>(wqkv, wqh, wql, nw);
  split2_kernel<<<dim3((np + 255) / 256), dim3(256), 0, stream>>>(wproj, wph, wpl, np);

  qkv_gemm_kernel<<<dim3(3 * DIM / 128, BL / 128), dim3(256), 0, stream>>>(
      xh, xl, wqh, wql, v0, rcos, rsin, lamp, qb, kb, vbT, vout);

  flash_kernel<<<dim3(Bs * NH * (Ls / 64)), dim3(256), 0, stream>>>(qb, kb, vbT, aoh, aol);

  proj_gemm_kernel<<<dim3(DIM / 128, BL / 128), dim3(256), 0, stream>>>(aoh, aol, wph, wpl, out);
}

// Round 3
// 247.907 us; speedup vs baseline: 1.8344x; 1.3460x over previous
//
#include <hip/hip_runtime.h>

typedef _Float16 f16;
typedef _Float16 f16x8 __attribute__((ext_vector_type(8)));
typedef _Float16 f16x4 __attribute__((ext_vector_type(4)));
typedef float f32x4 __attribute__((ext_vector_type(4)));

#define MFMA16(a, b, c) __builtin_amdgcn_mfma_f32_16x16x32_f16((a), (b), (c), 0, 0, 0)

constexpr int Bs = 2, Ls = 2048, DIM = 1024, NH = 16, HD = 64;
constexpr int BL = Bs * Ls;  // 4096
constexpr float EPSV = 1e-6f;
constexpr float SCALE = 0.125f;  // 1/sqrt(64)

// async global->LDS, 16B per lane. LDS dest = wave-uniform base + lane*16.
__device__ __forceinline__ void async16(void* lds, const void* g) {
  __builtin_amdgcn_global_load_lds((const __attribute__((address_space(1))) void*)g,
                                   (__attribute__((address_space(3))) void*)lds, 16, 0, 0);
}

// ---------------- fp32 -> fp16 convert (vec4) ----------------
__global__ void cvt_kernel(const float* __restrict__ src, f16* __restrict__ dst, int n4) {
  int i = blockIdx.x * blockDim.x + threadIdx.x;
  if (i < n4) {
    float4 a = ((const float4*)src)[i];
    f16x4 o = {(f16)a.x, (f16)a.y, (f16)a.z, (f16)a.w};
    ((f16x4*)dst)[i] = o;
  }
}

// ============ QKV GEMM: 128x128 tile, BK=64, fp16 single-term, fused epilogue ============
// 256 thr = 4 waves in 2x2; each wave owns a 64x64 quadrant (4x4 16x16 tiles).
// LDS rows are 128B (64 f16) -> XOR swizzle over all 8 16B-chunks: frag b128 reads are
// 2-way max (free). Swizzle applied via the GLOBAL address (global_load_lds writes lane*16).
__global__ __launch_bounds__(256) void qkv_gemm_kernel(
    const f16* __restrict__ A, const f16* __restrict__ W,
    const float* __restrict__ v0,
    const float* __restrict__ rcos, const float* __restrict__ rsin,
    const float* __restrict__ lamp,
    f16* __restrict__ qb, f16* __restrict__ kb, f16* __restrict__ vbT,
    float* __restrict__ vout) {
  constexpr int K = DIM;
  __shared__ alignas(16) f16 sA[128 * 64];
  __shared__ alignas(16) f16 sB[128 * 64];
  const int tid = threadIdx.x;
  const int w = tid >> 6, lane = tid & 63, ln = lane & 15, quad = lane >> 4;
  const int wm = w >> 1, wn = w & 1;
  const int m0 = blockIdx.y * 128, n0 = blockIdx.x * 128;

  int srow[4], scol[4];
#pragma unroll
  for (int s = 0; s < 4; ++s) {
    int lc = tid + s * 256;          // LDS chunk 0..1023
    int r = lc >> 3;                 // row 0..127
    srow[s] = r;
    scol[s] = ((lc & 7) ^ (r & 7)) * 8;  // permuted global chunk -> elems
  }

  f32x4 acc[4][4] = {};

  for (int k0 = 0; k0 < K; k0 += 64) {
#pragma unroll
    for (int s = 0; s < 4; ++s) {
      int lc = tid + s * 256;
      async16(&sA[lc * 8], A + (size_t)(m0 + srow[s]) * K + k0 + scol[s]);
      async16(&sB[lc * 8], W + (size_t)(n0 + srow[s]) * K + k0 + scol[s]);
    }
    __syncthreads();
#pragma unroll
    for (int kk = 0; kk < 2; ++kk) {
      f16x8 a[4];
#pragma unroll
      for (int mi = 0; mi < 4; ++mi) {
        int r = wm * 64 + mi * 16 + ln;
        a[mi] = *(const f16x8*)&sA[r * 64 + (((kk * 4 + quad) ^ (r & 7)) * 8)];
      }
#pragma unroll
      for (int ni = 0; ni < 4; ++ni) {
        int r = wn * 64 + ni * 16 + ln;
        f16x8 b = *(const f16x8*)&sB[r * 64 + (((kk * 4 + quad) ^ (r & 7)) * 8)];
#pragma unroll
        for (int mi = 0; mi < 4; ++mi) acc[mi][ni] = MFMA16(a[mi], b, acc[mi][ni]);
      }
    }
    __syncthreads();
  }

  // Epilogue. Wave covers one head (64 cols). C/D: col=ln (in ni tile), row=quad*4+rg (in mi tile).
  const int nb = n0 + wn * 64;
  const int nsec = nb >> 10;        // 0=q, 1=k, 2=v
  const int h = (nb & 1023) >> 6;   // head

  if (nsec == 2) {
    const float lam = lamp[0];
#pragma unroll
    for (int mi = 0; mi < 4; ++mi) {
#pragma unroll
      for (int rg = 0; rg < 4; ++rg) {
        int row = m0 + wm * 64 + mi * 16 + quad * 4 + rg;
        int b = row >> 11, l = row & 2047;
        size_t base = ((size_t)(b * NH + h) * Ls + l) * HD;
        int lt = l & 63;
        int pos = ((lt & 15) << 2) | (lt >> 4);  // key-interleave for packed P writes in flash
        size_t tb = ((size_t)(b * NH + h) * HD) * Ls + (l & ~63) + pos;
#pragma unroll
        for (int ni = 0; ni < 4; ++ni) {
          int d = ni * 16 + ln;
          float vnew = lam * acc[mi][ni][rg] + (1.0f - lam) * v0[base + d];
          vout[base + d] = vnew;                     // fp32 output #1 (b,h,l,d)
          vbT[tb + (size_t)d * Ls] = (f16)vnew;      // (b,h,d, tile*64+pos) for flash PV
        }
      }
    }
  } else {
    f16* dst = nsec ? kb : qb;
    const float ratio = sqrtf(logf(2048.0f) / logf(1040.0f));
#pragma unroll
    for (int mi = 0; mi < 4; ++mi) {
#pragma unroll
      for (int rg = 0; rg < 4; ++rg) {
        int row = m0 + wm * 64 + mi * 16 + quad * 4 + rg;
        int b = row >> 11, l = row & 2047;
        float vals[4];
#pragma unroll
        for (int ni = 0; ni < 4; ++ni) vals[ni] = acc[mi][ni][rg];
        // RoPE: pair (d, d+32) == (vals[t], vals[t+2]), j = t*16+ln
#pragma unroll
        for (int t = 0; t < 2; ++t) {
          int j = t * 16 + ln;
          float c = rcos[l * 32 + j], s = rsin[l * 32 + j];
          float x1 = vals[t], x2 = vals[t + 2];
          vals[t] = x1 * c + x2 * s;
          vals[t + 2] = -x1 * s + x2 * c;
        }
        if (nsec) {
#pragma unroll
          for (int ni = 0; ni < 4; ++ni) vals[ni] *= ratio;
        }
        float ms = vals[0] * vals[0] + vals[1] * vals[1] + vals[2] * vals[2] + vals[3] * vals[3];
        ms += __shfl_xor(ms, 1);
        ms += __shfl_xor(ms, 2);
        ms += __shfl_xor(ms, 4);
        ms += __shfl_xor(ms, 8);
        float rn = rsqrtf(ms * (1.0f / 64.0f) + EPSV);
        size_t base = ((size_t)(b * NH + h) * Ls + l) * HD;
#pragma unroll
        for (int ni = 0; ni < 4; ++ni) dst[base + ni * 16 + ln] = (f16)(vals[ni] * rn);
      }
    }
  }
}

// ============ Flash attention: 128-row Q tile, reg-prefetch dbuf K/V, packed P ============
// One block per (b, h, 128-row q tile); wave w owns 16-row strips at st*64 + w*16, st=0,1.
// sP wave-private -> no barrier around the P LDS roundtrip. One barrier per k-tile.
__global__ __launch_bounds__(256) void flash_kernel(
    const f16* __restrict__ qg, const f16* __restrict__ kg, const f16* __restrict__ vtg,
    f16* __restrict__ ao) {
  __shared__ alignas(16) f16 sQ[128 * 72];
  __shared__ alignas(16) f16 sK[2][64 * 72];
  __shared__ alignas(16) f16 sVT[2][64 * 72];  // [d][pos] (pre-interleaved keys)
  __shared__ alignas(16) f16 sP[128 * 72];     // [qrow][pos]
  const int tid = threadIdx.x;
  const int w = tid >> 6, lane = tid & 63, ln = lane & 15, quad = lane >> 4;
  const int bx = blockIdx.x;
  const int qt = bx & 15, h = (bx >> 4) & 15, b = bx >> 8;
  const f16* Qh = qg + (size_t)(b * NH + h) * Ls * HD;
  const f16* Kh = kg + (size_t)(b * NH + h) * Ls * HD;
  const f16* VTh = vtg + (size_t)(b * NH + h) * HD * Ls;
  const int q0 = qt * 128;

  // stage Q (128x64) + K/VT tile 0 (64x64 each)
#pragma unroll
  for (int s = 0; s < 4; ++s) {
    int e = tid + s * 256, row = e >> 3, c8 = (e & 7) * 8;
    *(f16x8*)&sQ[row * 72 + c8] = *(const f16x8*)&Qh[(size_t)(q0 + row) * HD + c8];
  }
#pragma unroll
  for (int s = 0; s < 2; ++s) {
    int e = tid + s * 256, row = e >> 3, c8 = (e & 7) * 8;
    *(f16x8*)&sK[0][row * 72 + c8] = *(const f16x8*)&Kh[(size_t)row * HD + c8];
    *(f16x8*)&sVT[0][row * 72 + c8] = *(const f16x8*)&VTh[(size_t)row * Ls + c8];
  }
  __syncthreads();

  f16x8 aq[2][2];
#pragma unroll
  for (int st = 0; st < 2; ++st)
#pragma unroll
    for (int kk = 0; kk < 2; ++kk)
      aq[st][kk] = *(const f16x8*)&sQ[(st * 64 + w * 16 + ln) * 72 + kk * 32 + quad * 8];

  f32x4 O[2][4] = {};
  float rsum[2][4] = {};

  for (int kt = 0; kt < 32; ++kt) {
    const int cur = kt & 1;
    f16x8 kr[2], vr[2];
    if (kt < 31) {  // prefetch next k-tile into registers; overlaps this tile's compute
      const int k0n = (kt + 1) * 64;
#pragma unroll
      for (int s = 0; s < 2; ++s) {
        int e = tid + s * 256, row = e >> 3, c8 = (e & 7) * 8;
        kr[s] = *(const f16x8*)&Kh[(size_t)(k0n + row) * HD + c8];
        vr[s] = *(const f16x8*)&VTh[(size_t)row * Ls + k0n + c8];
      }
    }

    // S = Q K^T
    f32x4 S[2][4];
#pragma unroll
    for (int nt = 0; nt < 4; ++nt) {
      f16x8 bk0 = *(const f16x8*)&sK[cur][(nt * 16 + ln) * 72 + quad * 8];
      f16x8 bk1 = *(const f16x8*)&sK[cur][(nt * 16 + ln) * 72 + 32 + quad * 8];
#pragma unroll
      for (int st = 0; st < 2; ++st) {
        f32x4 z = {};
        z = MFMA16(aq[st][0], bk0, z);
        z = MFMA16(aq[st][1], bk1, z);
        S[st][nt] = z;
      }
    }

    // p = exp(score) (no max-shift: |score| <= 8.4 post-RMSnorm), packed b64 P writes.
    // P[qrow][pos] with pos = (key%16)*4 + key/16: thread's 4 nt-values are contiguous.
#pragma unroll
    for (int st = 0; st < 2; ++st) {
#pragma unroll
      for (int rg = 0; rg < 4; ++rg) {
        float p0 = __expf(S[st][0][rg] * SCALE);
        float p1 = __expf(S[st][1][rg] * SCALE);
        float p2 = __expf(S[st][2][rg] * SCALE);
        float p3 = __expf(S[st][3][rg] * SCALE);
        rsum[st][rg] += p0 + p1 + p2 + p3;
        f16x4 pk = {(f16)p0, (f16)p1, (f16)p2, (f16)p3};
        *(f16x4*)&sP[(st * 64 + w * 16 + quad * 4 + rg) * 72 + ln * 4] = pk;
      }
    }

    // O += P V  (A = P rows [q][pos], B = VT [d][pos]; k permuted consistently)
    f16x8 ap[2][2];
#pragma unroll
    for (int st = 0; st < 2; ++st) {
      ap[st][0] = *(const f16x8*)&sP[(st * 64 + w * 16 + ln) * 72 + quad * 8];
      ap[st][1] = *(const f16x8*)&sP[(st * 64 + w * 16 + ln) * 72 + 32 + quad * 8];
    }
#pragma unroll
    for (int nt = 0; nt < 4; ++nt) {
      f16x8 bv0 = *(const f16x8*)&sVT[cur][(nt * 16 + ln) * 72 + quad * 8];
      f16x8 bv1 = *(const f16x8*)&sVT[cur][(nt * 16 + ln) * 72 + 32 + quad * 8];
#pragma unroll
      for (int st = 0; st < 2; ++st) {
        O[st][nt] = MFMA16(ap[st][0], bv0, O[st][nt]);
        O[st][nt] = MFMA16(ap[st][1], bv1, O[st][nt]);
      }
    }

    if (kt < 31) {
      const int nxt = cur ^ 1;
#pragma unroll
      for (int s = 0; s < 2; ++s) {
        int e = tid + s * 256, row = e >> 3, c8 = (e & 7) * 8;
        *(f16x8*)&sK[nxt][row * 72 + c8] = kr[s];
        *(f16x8*)&sVT[nxt][row * 72 + c8] = vr[s];
      }
    }
    __syncthreads();
  }

  // epilogue: reduce row sums once, normalize, store fp16 attn-out in (b,l,dim)
#pragma unroll
  for (int st = 0; st < 2; ++st) {
#pragma unroll
    for (int rg = 0; rg < 4; ++rg) {
      float rs = rsum[st][rg];
      rs += __shfl_xor(rs, 1);
      rs += __shfl_xor(rs, 2);
      rs += __shfl_xor(rs, 4);
      rs += __shfl_xor(rs, 8);
      float inv = 1.0f / rs;
      int l = q0 + st * 64 + w * 16 + quad * 4 + rg;
      size_t orow = ((size_t)b * Ls + l) * DIM + h * HD;
#pragma unroll
      for (int nt = 0; nt < 4; ++nt)
        ao[orow + nt * 16 + ln] = (f16)(O[st][nt][rg] * inv);
    }
  }
}

// ============ proj GEMM: same fp16 BK=64 core, fp32 out ============
__global__ __launch_bounds__(256) void proj_gemm_kernel(
    const f16* __restrict__ A, const f16* __restrict__ W, float* __restrict__ out) {
  constexpr int K = DIM;
  __shared__ alignas(16) f16 sA[128 * 64];
  __shared__ alignas(16) f16 sB[128 * 64];
  const int tid = threadIdx.x;
  const int w = tid >> 6, lane = tid & 63, ln = lane & 15, quad = lane >> 4;
  const int wm = w >> 1, wn = w & 1;
  const int m0 = blockIdx.y * 128, n0 = blockIdx.x * 128;

  int srow[4], scol[4];
#pragma unroll
  for (int s = 0; s < 4; ++s) {
    int lc = tid + s * 256;
    int r = lc >> 3;
    srow[s] = r;
    scol[s] = ((lc & 7) ^ (r & 7)) * 8;
  }

  f32x4 acc[4][4] = {};

  for (int k0 = 0; k0 < K; k0 += 64) {
#pragma unroll
    for (int s = 0; s < 4; ++s) {
      int lc = tid + s * 256;
      async16(&sA[lc * 8], A + (size_t)(m0 + srow[s]) * K + k0 + scol[s]);
      async16(&sB[lc * 8], W + (size_t)(n0 + srow[s]) * K + k0 + scol[s]);
    }
    __syncthreads();
#pragma unroll
    for (int kk = 0; kk < 2; ++kk) {
      f16x8 a[4];
#pragma unroll
      for (int mi = 0; mi < 4; ++mi) {
        int r = wm * 64 + mi * 16 + ln;
        a[mi] = *(const f16x8*)&sA[r * 64 + (((kk * 4 + quad) ^ (r & 7)) * 8)];
      }
#pragma unroll
      for (int ni = 0; ni < 4; ++ni) {
        int r = wn * 64 + ni * 16 + ln;
        f16x8 b = *(const f16x8*)&sB[r * 64 + (((kk * 4 + quad) ^ (r & 7)) * 8)];
#pragma unroll
        for (int mi = 0; mi < 4; ++mi) acc[mi][ni] = MFMA16(a[mi], b, acc[mi][ni]);
      }
    }
    __syncthreads();
  }

#pragma unroll
  for (int mi = 0; mi < 4; ++mi) {
#pragma unroll
    for (int rg = 0; rg < 4; ++rg) {
      int row = m0 + wm * 64 + mi * 16 + quad * 4 + rg;
      size_t o = (size_t)row * DIM + n0 + wn * 64;
#pragma unroll
      for (int ni = 0; ni < 4; ++ni) out[o + ni * 16 + ln] = acc[mi][ni][rg];
    }
  }
}

extern "C" void kernel_launch(void* const* d_in, const int* in_sizes, int n_in,
                              void* d_out, int out_size, void* d_ws, size_t ws_size,
                              hipStream_t stream) {
  (void)in_sizes; (void)n_in; (void)out_size; (void)ws_size;
  const float* x = (const float*)d_in[0];
  const float* v0 = (const float*)d_in[1];
  const float* rcos = (const float*)d_in[2];
  const float* rsin = (const float*)d_in[3];
  const float* wqkv = (const float*)d_in[4];
  const float* wproj = (const float*)d_in[5];
  const float* lamp = (const float*)d_in[6];
  float* out = (float*)d_out;
  float* vout = out + (size_t)BL * DIM;  // output #1: blended v, (B,H,L,HD)

  char* p = (char*)d_ws;
  auto take = [&](size_t n) { char* q = p; p += ((n + 255) / 256) * 256; return q; };
  f16* xf = (f16*)take((size_t)BL * DIM * 2);
  f16* wqf = (f16*)take((size_t)3 * DIM * DIM * 2);
  f16* wpf = (f16*)take((size_t)DIM * DIM * 2);
  f16* qb = (f16*)take((size_t)BL * DIM * 2);
  f16* kb = (f16*)take((size_t)BL * DIM * 2);
  f16* vbT = (f16*)take((size_t)BL * DIM * 2);  // (b,h,d, key-interleaved l)
  f16* ao = xf;  // x dead after qkv_gemm; reuse (stream-ordered)

  cvt_kernel<<<dim3(BL * DIM / 4 / 256), dim3(256), 0, stream>>>(x, xf, BL * DIM / 4);
  cvt_kernel<<<dim3(3 * DIM * DIM / 4 / 256), dim3(256), 0, stream>>>(wqkv, wqf, 3 * DIM * DIM / 4);
  cvt_kernel<<<dim3(DIM * DIM / 4 / 256), dim3(256), 0, stream>>>(wproj, wpf, DIM * DIM / 4);

  qkv_gemm_kernel<<<dim3(3 * DIM / 128, BL / 128), dim3(256), 0, stream>>>(
      xf, wqf, v0, rcos, rsin, lamp, qb, kb, vbT, vout);

  flash_kernel<<<dim3(Bs * NH * (Ls / 128)), dim3(256), 0, stream>>>(qb, kb, vbT, ao);

  proj_gemm_kernel<<<dim3(DIM / 128, BL / 128), dim3(256), 0, stream>>>(ao, wpf, out);
}

// Round 4
// 242.358 us; speedup vs baseline: 1.8764x; 1.0229x over previous
//
#include <hip/hip_runtime.h>

typedef _Float16 f16;
typedef _Float16 f16x8 __attribute__((ext_vector_type(8)));
typedef _Float16 f16x4 __attribute__((ext_vector_type(4)));
typedef float f32x4 __attribute__((ext_vector_type(4)));

#define MFMA16(a, b, c) __builtin_amdgcn_mfma_f32_16x16x32_f16((a), (b), (c), 0, 0, 0)

constexpr int Bs = 2, Ls = 2048, DIM = 1024, NH = 16, HD = 64;
constexpr int BL = Bs * Ls;  // 4096
constexpr float EPSV = 1e-6f;
constexpr float SCALE = 0.125f;  // 1/sqrt(64)

// async global->LDS, 16B per lane. LDS dest = wave-uniform base + lane*16. Zero VGPR cost.
__device__ __forceinline__ void async16(void* lds, const void* g) {
  __builtin_amdgcn_global_load_lds((const __attribute__((address_space(1))) void*)g,
                                   (__attribute__((address_space(3))) void*)lds, 16, 0, 0);
}

// ---------------- fp32 -> fp16 convert, all three tensors in one launch ----------------
__global__ void cvt_all_kernel(const float* __restrict__ x, const float* __restrict__ wq,
                               const float* __restrict__ wp, f16* __restrict__ xf,
                               f16* __restrict__ wqf, f16* __restrict__ wpf) {
  constexpr int NX4 = BL * DIM / 4;           // 1048576
  constexpr int NW4 = 3 * DIM * DIM / 4;      // 786432
  int i = blockIdx.x * blockDim.x + threadIdx.x;
  const float4* src;
  f16x4* dst;
  int j;
  if (i < NX4) {
    src = (const float4*)x; dst = (f16x4*)xf; j = i;
  } else if (i < NX4 + NW4) {
    src = (const float4*)wq; dst = (f16x4*)wqf; j = i - NX4;
  } else {
    src = (const float4*)wp; dst = (f16x4*)wpf; j = i - NX4 - NW4;
  }
  float4 a = src[j];
  f16x4 o = {(f16)a.x, (f16)a.y, (f16)a.z, (f16)a.w};
  dst[j] = o;
}

// ============ QKV GEMM: 128x128 tile, BK=64, LDS double-buffered async staging ============
// 256 thr = 4 waves in 2x2; each wave owns a 64x64 quadrant (4x4 16x16 tiles).
// Pipeline: issue async16 prefetch of tile k+1 -> compute tile k -> barrier (vmcnt drain
// lands after compute has hidden the load latency). One barrier per K-iter.
// XOR swizzle over all 8 16B-chunks of the 128B row -> frag b128 reads 2-way max (free).
__global__ __launch_bounds__(256) void qkv_gemm_kernel(
    const f16* __restrict__ A, const f16* __restrict__ W,
    const float* __restrict__ v0,
    const float* __restrict__ rcos, const float* __restrict__ rsin,
    const float* __restrict__ lamp,
    f16* __restrict__ qb, f16* __restrict__ kb, f16* __restrict__ vbT,
    float* __restrict__ vout) {
  constexpr int K = DIM;
  __shared__ alignas(16) f16 sA[2][128 * 64];
  __shared__ alignas(16) f16 sB[2][128 * 64];
  const int tid = threadIdx.x;
  const int w = tid >> 6, lane = tid & 63, ln = lane & 15, quad = lane >> 4;
  const int wm = w >> 1, wn = w & 1;
  const int m0 = blockIdx.y * 128, n0 = blockIdx.x * 128;

  int srow[4], scol[4];
#pragma unroll
  for (int s = 0; s < 4; ++s) {
    int lc = tid + s * 256;              // LDS chunk 0..1023
    int r = lc >> 3;                     // row 0..127
    srow[s] = r;
    scol[s] = ((lc & 7) ^ (r & 7)) * 8;  // permuted global chunk -> elems
  }

  auto stage = [&](int buf, int k0) {
#pragma unroll
    for (int s = 0; s < 4; ++s) {
      int lc = tid + s * 256;
      async16(&sA[buf][lc * 8], A + (size_t)(m0 + srow[s]) * K + k0 + scol[s]);
      async16(&sB[buf][lc * 8], W + (size_t)(n0 + srow[s]) * K + k0 + scol[s]);
    }
  };

  f32x4 acc[4][4] = {};
  stage(0, 0);
  __syncthreads();

  for (int it = 0; it < K / 64; ++it) {
    const int cur = it & 1;
    if (it + 1 < K / 64) stage(cur ^ 1, (it + 1) * 64);  // in flight during compute
#pragma unroll
    for (int kk = 0; kk < 2; ++kk) {
      f16x8 a[4];
#pragma unroll
      for (int mi = 0; mi < 4; ++mi) {
        int r = wm * 64 + mi * 16 + ln;
        a[mi] = *(const f16x8*)&sA[cur][r * 64 + (((kk * 4 + quad) ^ (r & 7)) * 8)];
      }
#pragma unroll
      for (int ni = 0; ni < 4; ++ni) {
        int r = wn * 64 + ni * 16 + ln;
        f16x8 b = *(const f16x8*)&sB[cur][r * 64 + (((kk * 4 + quad) ^ (r & 7)) * 8)];
#pragma unroll
        for (int mi = 0; mi < 4; ++mi) acc[mi][ni] = MFMA16(a[mi], b, acc[mi][ni]);
      }
    }
    __syncthreads();  // drains prefetch vmcnt + protects cur buffer for it+2
  }

  // Epilogue. Wave covers one head (64 cols). C/D: col=ln (in ni tile), row=quad*4+rg (in mi tile).
  const int nb = n0 + wn * 64;
  const int nsec = nb >> 10;        // 0=q, 1=k, 2=v
  const int h = (nb & 1023) >> 6;   // head

  if (nsec == 2) {
    const float lam = lamp[0];
#pragma unroll
    for (int mi = 0; mi < 4; ++mi) {
#pragma unroll
      for (int rg = 0; rg < 4; ++rg) {
        int row = m0 + wm * 64 + mi * 16 + quad * 4 + rg;
        int b = row >> 11, l = row & 2047;
        size_t base = ((size_t)(b * NH + h) * Ls + l) * HD;
        int lt = l & 63;
        int pos = ((lt & 15) << 2) | (lt >> 4);  // key-interleave for packed P writes in flash
        size_t tb = ((size_t)(b * NH + h) * HD) * Ls + (l & ~63) + pos;
#pragma unroll
        for (int ni = 0; ni < 4; ++ni) {
          int d = ni * 16 + ln;
          float vnew = lam * acc[mi][ni][rg] + (1.0f - lam) * v0[base + d];
          vout[base + d] = vnew;                     // fp32 output #1 (b,h,l,d)
          vbT[tb + (size_t)d * Ls] = (f16)vnew;      // (b,h,d, tile*64+pos) for flash PV
        }
      }
    }
  } else {
    f16* dst = nsec ? kb : qb;
    const float ratio = sqrtf(logf(2048.0f) / logf(1040.0f));
#pragma unroll
    for (int mi = 0; mi < 4; ++mi) {
#pragma unroll
      for (int rg = 0; rg < 4; ++rg) {
        int row = m0 + wm * 64 + mi * 16 + quad * 4 + rg;
        int b = row >> 11, l = row & 2047;
        float vals[4];
#pragma unroll
        for (int ni = 0; ni < 4; ++ni) vals[ni] = acc[mi][ni][rg];
        // RoPE: pair (d, d+32) == (vals[t], vals[t+2]), j = t*16+ln
#pragma unroll
        for (int t = 0; t < 2; ++t) {
          int j = t * 16 + ln;
          float c = rcos[l * 32 + j], s = rsin[l * 32 + j];
          float x1 = vals[t], x2 = vals[t + 2];
          vals[t] = x1 * c + x2 * s;
          vals[t + 2] = -x1 * s + x2 * c;
        }
        if (nsec) {
#pragma unroll
          for (int ni = 0; ni < 4; ++ni) vals[ni] *= ratio;
        }
        float ms = vals[0] * vals[0] + vals[1] * vals[1] + vals[2] * vals[2] + vals[3] * vals[3];
        ms += __shfl_xor(ms, 1);
        ms += __shfl_xor(ms, 2);
        ms += __shfl_xor(ms, 4);
        ms += __shfl_xor(ms, 8);
        float rn = rsqrtf(ms * (1.0f / 64.0f) + EPSV);
        size_t base = ((size_t)(b * NH + h) * Ls + l) * HD;
#pragma unroll
        for (int ni = 0; ni < 4; ++ni) dst[base + ni * 16 + ln] = (f16)(vals[ni] * rn);
      }
    }
  }
}

// ============ Flash attention: 128-row Q tile, reg-prefetch dbuf K/V, packed P ============
// One block per (b, h, 128-row q tile); wave w owns 16-row strips at st*64 + w*16, st=0,1.
// sP wave-private -> no barrier around the P LDS roundtrip. One barrier per k-tile.
__global__ __launch_bounds__(256) void flash_kernel(
    const f16* __restrict__ qg, const f16* __restrict__ kg, const f16* __restrict__ vtg,
    f16* __restrict__ ao) {
  __shared__ alignas(16) f16 sQ[128 * 72];
  __shared__ alignas(16) f16 sK[2][64 * 72];
  __shared__ alignas(16) f16 sVT[2][64 * 72];  // [d][pos] (pre-interleaved keys)
  __shared__ alignas(16) f16 sP[128 * 72];     // [qrow][pos]
  const int tid = threadIdx.x;
  const int w = tid >> 6, lane = tid & 63, ln = lane & 15, quad = lane >> 4;
  const int bx = blockIdx.x;
  const int qt = bx & 15, h = (bx >> 4) & 15, b = bx >> 8;
  const f16* Qh = qg + (size_t)(b * NH + h) * Ls * HD;
  const f16* Kh = kg + (size_t)(b * NH + h) * Ls * HD;
  const f16* VTh = vtg + (size_t)(b * NH + h) * HD * Ls;
  const int q0 = qt * 128;

  // stage Q (128x64) + K/VT tile 0 (64x64 each)
#pragma unroll
  for (int s = 0; s < 4; ++s) {
    int e = tid + s * 256, row = e >> 3, c8 = (e & 7) * 8;
    *(f16x8*)&sQ[row * 72 + c8] = *(const f16x8*)&Qh[(size_t)(q0 + row) * HD + c8];
  }
#pragma unroll
  for (int s = 0; s < 2; ++s) {
    int e = tid + s * 256, row = e >> 3, c8 = (e & 7) * 8;
    *(f16x8*)&sK[0][row * 72 + c8] = *(const f16x8*)&Kh[(size_t)row * HD + c8];
    *(f16x8*)&sVT[0][row * 72 + c8] = *(const f16x8*)&VTh[(size_t)row * Ls + c8];
  }
  __syncthreads();

  f16x8 aq[2][2];
#pragma unroll
  for (int st = 0; st < 2; ++st)
#pragma unroll
    for (int kk = 0; kk < 2; ++kk)
      aq[st][kk] = *(const f16x8*)&sQ[(st * 64 + w * 16 + ln) * 72 + kk * 32 + quad * 8];

  f32x4 O[2][4] = {};
  float rsum[2][4] = {};

  for (int kt = 0; kt < 32; ++kt) {
    const int cur = kt & 1;
    f16x8 kr[2], vr[2];
    if (kt < 31) {  // prefetch next k-tile into registers; overlaps this tile's compute
      const int k0n = (kt + 1) * 64;
#pragma unroll
      for (int s = 0; s < 2; ++s) {
        int e = tid + s * 256, row = e >> 3, c8 = (e & 7) * 8;
        kr[s] = *(const f16x8*)&Kh[(size_t)(k0n + row) * HD + c8];
        vr[s] = *(const f16x8*)&VTh[(size_t)row * Ls + k0n + c8];
      }
    }

    // S = Q K^T
    f32x4 S[2][4];
#pragma unroll
    for (int nt = 0; nt < 4; ++nt) {
      f16x8 bk0 = *(const f16x8*)&sK[cur][(nt * 16 + ln) * 72 + quad * 8];
      f16x8 bk1 = *(const f16x8*)&sK[cur][(nt * 16 + ln) * 72 + 32 + quad * 8];
#pragma unroll
      for (int st = 0; st < 2; ++st) {
        f32x4 z = {};
        z = MFMA16(aq[st][0], bk0, z);
        z = MFMA16(aq[st][1], bk1, z);
        S[st][nt] = z;
      }
    }

    // p = exp(score) (no max-shift: |score| <= 8.4 post-RMSnorm), packed b64 P writes.
    // P[qrow][pos] with pos = (key%16)*4 + key/16: thread's 4 nt-values are contiguous.
#pragma unroll
    for (int st = 0; st < 2; ++st) {
#pragma unroll
      for (int rg = 0; rg < 4; ++rg) {
        float p0 = __expf(S[st][0][rg] * SCALE);
        float p1 = __expf(S[st][1][rg] * SCALE);
        float p2 = __expf(S[st][2][rg] * SCALE);
        float p3 = __expf(S[st][3][rg] * SCALE);
        rsum[st][rg] += p0 + p1 + p2 + p3;
        f16x4 pk = {(f16)p0, (f16)p1, (f16)p2, (f16)p3};
        *(f16x4*)&sP[(st * 64 + w * 16 + quad * 4 + rg) * 72 + ln * 4] = pk;
      }
    }

    // O += P V  (A = P rows [q][pos], B = VT [d][pos]; k permuted consistently)
    f16x8 ap[2][2];
#pragma unroll
    for (int st = 0; st < 2; ++st) {
      ap[st][0] = *(const f16x8*)&sP[(st * 64 + w * 16 + ln) * 72 + quad * 8];
      ap[st][1] = *(const f16x8*)&sP[(st * 64 + w * 16 + ln) * 72 + 32 + quad * 8];
    }
#pragma unroll
    for (int nt = 0; nt < 4; ++nt) {
      f16x8 bv0 = *(const f16x8*)&sVT[cur][(nt * 16 + ln) * 72 + quad * 8];
      f16x8 bv1 = *(const f16x8*)&sVT[cur][(nt * 16 + ln) * 72 + 32 + quad * 8];
#pragma unroll
      for (int st = 0; st < 2; ++st) {
        O[st][nt] = MFMA16(ap[st][0], bv0, O[st][nt]);
        O[st][nt] = MFMA16(ap[st][1], bv1, O[st][nt]);
      }
    }

    if (kt < 31) {
      const int nxt = cur ^ 1;
#pragma unroll
      for (int s = 0; s < 2; ++s) {
        int e = tid + s * 256, row = e >> 3, c8 = (e & 7) * 8;
        *(f16x8*)&sK[nxt][row * 72 + c8] = kr[s];
        *(f16x8*)&sVT[nxt][row * 72 + c8] = vr[s];
      }
    }
    __syncthreads();
  }

  // epilogue: reduce row sums once, normalize, store fp16 attn-out in (b,l,dim)
#pragma unroll
  for (int st = 0; st < 2; ++st) {
#pragma unroll
    for (int rg = 0; rg < 4; ++rg) {
      float rs = rsum[st][rg];
      rs += __shfl_xor(rs, 1);
      rs += __shfl_xor(rs, 2);
      rs += __shfl_xor(rs, 4);
      rs += __shfl_xor(rs, 8);
      float inv = 1.0f / rs;
      int l = q0 + st * 64 + w * 16 + quad * 4 + rg;
      size_t orow = ((size_t)b * Ls + l) * DIM + h * HD;
#pragma unroll
      for (int nt = 0; nt < 4; ++nt)
        ao[orow + nt * 16 + ln] = (f16)(O[st][nt][rg] * inv);
    }
  }
}

// ============ proj GEMM: fp16 BK=64 core, LDS double-buffered, fp32 out ============
__global__ __launch_bounds__(256) void proj_gemm_kernel(
    const f16* __restrict__ A, const f16* __restrict__ W, float* __restrict__ out) {
  constexpr int K = DIM;
  __shared__ alignas(16) f16 sA[2][128 * 64];
  __shared__ alignas(16) f16 sB[2][128 * 64];
  const int tid = threadIdx.x;
  const int w = tid >> 6, lane = tid & 63, ln = lane & 15, quad = lane >> 4;
  const int wm = w >> 1, wn = w & 1;
  const int m0 = blockIdx.y * 128, n0 = blockIdx.x * 128;

  int srow[4], scol[4];
#pragma unroll
  for (int s = 0; s < 4; ++s) {
    int lc = tid + s * 256;
    int r = lc >> 3;
    srow[s] = r;
    scol[s] = ((lc & 7) ^ (r & 7)) * 8;
  }

  auto stage = [&](int buf, int k0) {
#pragma unroll
    for (int s = 0; s < 4; ++s) {
      int lc = tid + s * 256;
      async16(&sA[buf][lc * 8], A + (size_t)(m0 + srow[s]) * K + k0 + scol[s]);
      async16(&sB[buf][lc * 8], W + (size_t)(n0 + srow[s]) * K + k0 + scol[s]);
    }
  };

  f32x4 acc[4][4] = {};
  stage(0, 0);
  __syncthreads();

  for (int it = 0; it < K / 64; ++it) {
    const int cur = it & 1;
    if (it + 1 < K / 64) stage(cur ^ 1, (it + 1) * 64);
#pragma unroll
    for (int kk = 0; kk < 2; ++kk) {
      f16x8 a[4];
#pragma unroll
      for (int mi = 0; mi < 4; ++mi) {
        int r = wm * 64 + mi * 16 + ln;
        a[mi] = *(const f16x8*)&sA[cur][r * 64 + (((kk * 4 + quad) ^ (r & 7)) * 8)];
      }
#pragma unroll
      for (int ni = 0; ni < 4; ++ni) {
        int r = wn * 64 + ni * 16 + ln;
        f16x8 b = *(const f16x8*)&sB[cur][r * 64 + (((kk * 4 + quad) ^ (r & 7)) * 8)];
#pragma unroll
        for (int mi = 0; mi < 4; ++mi) acc[mi][ni] = MFMA16(a[mi], b, acc[mi][ni]);
      }
    }
    __syncthreads();
  }

#pragma unroll
  for (int mi = 0; mi < 4; ++mi) {
#pragma unroll
    for (int rg = 0; rg < 4; ++rg) {
      int row = m0 + wm * 64 + mi * 16 + quad * 4 + rg;
      size_t o = (size_t)row * DIM + n0 + wn * 64;
#pragma unroll
      for (int ni = 0; ni < 4; ++ni) out[o + ni * 16 + ln] = acc[mi][ni][rg];
    }
  }
}

extern "C" void kernel_launch(void* const* d_in, const int* in_sizes, int n_in,
                              void* d_out, int out_size, void* d_ws, size_t ws_size,
                              hipStream_t stream) {
  (void)in_sizes; (void)n_in; (void)out_size; (void)ws_size;
  const float* x = (const float*)d_in[0];
  const float* v0 = (const float*)d_in[1];
  const float* rcos = (const float*)d_in[2];
  const float* rsin = (const float*)d_in[3];
  const float* wqkv = (const float*)d_in[4];
  const float* wproj = (const float*)d_in[5];
  const float* lamp = (const float*)d_in[6];
  float* out = (float*)d_out;
  float* vout = out + (size_t)BL * DIM;  // output #1: blended v, (B,H,L,HD)

  char* p = (char*)d_ws;
  auto take = [&](size_t n) { char* q = p; p += ((n + 255) / 256) * 256; return q; };
  f16* xf = (f16*)take((size_t)BL * DIM * 2);
  f16* wqf = (f16*)take((size_t)3 * DIM * DIM * 2);
  f16* wpf = (f16*)take((size_t)DIM * DIM * 2);
  f16* qb = (f16*)take((size_t)BL * DIM * 2);
  f16* kb = (f16*)take((size_t)BL * DIM * 2);
  f16* vbT = (f16*)take((size_t)BL * DIM * 2);  // (b,h,d, key-interleaved l)
  f16* ao = xf;  // x dead after qkv_gemm; reuse (stream-ordered)

  constexpr int NCVT4 = (BL * DIM + 3 * DIM * DIM + DIM * DIM) / 4;  // 2097152
  cvt_all_kernel<<<dim3(NCVT4 / 256), dim3(256), 0, stream>>>(x, wqkv, wproj, xf, wqf, wpf);

  qkv_gemm_kernel<<<dim3(3 * DIM / 128, BL / 128), dim3(256), 0, stream>>>(
      xf, wqf, v0, rcos, rsin, lamp, qb, kb, vbT, vout);

  flash_kernel<<<dim3(Bs * NH * (Ls / 128)), dim3(256), 0, stream>>>(qb, kb, vbT, ao);

  proj_gemm_kernel<<<dim3(DIM / 128, BL / 128), dim3(256), 0, stream>>>(ao, wpf, out);
}